// Round 13
// baseline (741.845 us; speedup 1.0000x reference)
//
#include <hip/hip_runtime.h>
#include <math.h>

#define NB 16
#define NF 768
#define NN 1024
#define KSEL 30

// ---------------- K1: per-(b,f) mean and 1/(std+1e-6); one wave per row
__global__ __launch_bounds__(256) void k_stats(const float* __restrict__ data,
                                               double* __restrict__ meanv,
                                               double* __restrict__ invv) {
    int bf = blockIdx.x * 4 + (threadIdx.x >> 6);
    int lane = threadIdx.x & 63;
    const float4* p = reinterpret_cast<const float4*>(data + (size_t)bf * NN);
    double s = 0.0, s2 = 0.0;
    #pragma unroll
    for (int r = 0; r < 4; ++r) {
        float4 v = p[r * 64 + lane];
        s  += (double)v.x + (double)v.y + (double)v.z + (double)v.w;
        s2 += (double)v.x * (double)v.x + (double)v.y * (double)v.y +
              (double)v.z * (double)v.z + (double)v.w * (double)v.w;
    }
    #pragma unroll
    for (int off = 1; off < 64; off <<= 1) {
        s  += __shfl_xor(s, off);
        s2 += __shfl_xor(s2, off);
    }
    if (lane == 0) {
        double mean = s / (double)NN;
        double var = (s2 - s * mean) / (double)(NN - 1);
        if (var < 0.0) var = 0.0;
        meanv[bf] = mean;
        invv[bf]  = 1.0 / (sqrt(var) + 1e-6);
    }
}

// ---------------- K2a: partial sq over f-chunks of 96 (512 blocks for parallelism)
__global__ __launch_bounds__(256) void k_sq1(const float* __restrict__ data,
                                             const double* __restrict__ meanv,
                                             const double* __restrict__ invv,
                                             double* __restrict__ psum) {
    int b = blockIdx.x >> 2;
    int n = ((blockIdx.x & 3) << 8) + threadIdx.x;
    int y = blockIdx.y;                 // f-chunk 0..7
    const float* base = data + (size_t)b * NF * NN;
    const double* mb = meanv + (size_t)b * NF;
    const double* ib = invv + (size_t)b * NF;
    double acc = 0.0;
    int f0 = y * 96;
    for (int f = f0; f < f0 + 96; ++f) {
        float x = base[(size_t)f * NN + n];
        float xn = (float)(((double)x - mb[f]) * ib[f]);
        acc = fma((double)xn, (double)xn, acc);
    }
    psum[((size_t)(b * 8 + y)) * NN + n] = acc;
}

// ---------------- K2b: reduce 8 partials -> sq[b,n]
__global__ __launch_bounds__(256) void k_sq2(const double* __restrict__ psum,
                                             double* __restrict__ sq) {
    int g = blockIdx.x * 256 + threadIdx.x;   // 0..16383
    int b = g >> 10, n = g & (NN - 1);
    double acc = 0.0;
    #pragma unroll
    for (int y = 0; y < 8; ++y) acc += psum[((size_t)(b * 8 + y)) * NN + n];
    sq[g] = acc;
}

// ---------------- K0: deg[n] = row-sum of adj; one wave per row
__global__ __launch_bounds__(256) void k_deg(const float* __restrict__ adj, float* __restrict__ deg) {
    int n = blockIdx.x * 4 + (threadIdx.x >> 6);
    int lane = threadIdx.x & 63;
    const float4* row = reinterpret_cast<const float4*>(adj + (size_t)n * NN);
    float s = 0.0f;
    #pragma unroll
    for (int r = 0; r < 4; ++r) {
        float4 v = row[r * 64 + lane];
        s += v.x + v.y + v.z + v.w;
    }
    #pragma unroll
    for (int off = 1; off < 64; off <<= 1) s += __shfl_xor(s, off);
    if (lane == 0) deg[n] = s;
}

// ---------------- K3: symmetric batched Gram + d2 epilogue (f64 accum)
// Round-12 conflict-free f64-LDS structure + T14 async-STAGE: next chunk's
// raw float2s are loaded into registers right after the mid-barrier, so
// global latency hides under the 32-k-step compute. Normalization happens
// in the write phase. All prefetch arrays fully unrolled (const indices).
__global__ __launch_bounds__(256) void k_gemm_sym(const float* __restrict__ data,
                                                  const double* __restrict__ meanv,
                                                  const double* __restrict__ invv,
                                                  const double* __restrict__ sq,
                                                  double* __restrict__ d2buf, int b0) {
    __shared__ double As[32][64];
    __shared__ double Bs[32][64];
    int tid = threadIdx.x;
    int tx = tid & 15, ty = tid >> 4;
    // triangular decode over 16x16 tiles of 64: t in [0,136), ti <= tj
    int t = blockIdx.x;
    int ti = 0, rem = t;
    while (rem >= 16 - ti) { rem -= 16 - ti; ++ti; }
    int tj = ti + rem;
    int n0 = ti * 64, m0 = tj * 64;
    int bb = blockIdx.z;
    int b = b0 + bb;
    const float* base = data + (size_t)b * NF * NN;
    const double* mb = meanv + (size_t)b * NF;
    const double* ib = invv + (size_t)b * NF;
    double acc[4][4] = {{0.0}};

    float2 ra[4], rc[4];
    // prologue: load chunk 0
    #pragma unroll
    for (int r = 0; r < 4; ++r) {
        int idx = r * 256 + tid;
        int k = idx >> 5, c2 = idx & 31;
        ra[r] = *reinterpret_cast<const float2*>(base + (size_t)k * NN + n0 + c2 * 2);
        rc[r] = *reinterpret_cast<const float2*>(base + (size_t)k * NN + m0 + c2 * 2);
    }

    for (int f0 = 0; f0 < NF; f0 += 32) {
        // write phase: normalize regs -> LDS (16B-stride double2 = 2-way, free)
        #pragma unroll
        for (int r = 0; r < 4; ++r) {
            int idx = r * 256 + tid;
            int k = idx >> 5, c2 = idx & 31;
            double mk = mb[f0 + k], ik = ib[f0 + k];
            double2 da, dc;
            da.x = (double)(float)(((double)ra[r].x - mk) * ik);
            da.y = (double)(float)(((double)ra[r].y - mk) * ik);
            dc.x = (double)(float)(((double)rc[r].x - mk) * ik);
            dc.y = (double)(float)(((double)rc[r].y - mk) * ik);
            *reinterpret_cast<double2*>(&As[k][c2 * 2]) = da;
            *reinterpret_cast<double2*>(&Bs[k][c2 * 2]) = dc;
        }
        __syncthreads();
        // issue next chunk's loads; latency hides under compute below
        if (f0 + 32 < NF) {
            #pragma unroll
            for (int r = 0; r < 4; ++r) {
                int idx = r * 256 + tid;
                int k = idx >> 5, c2 = idx & 31;
                ra[r] = *reinterpret_cast<const float2*>(base + (size_t)(f0 + 32 + k) * NN + n0 + c2 * 2);
                rc[r] = *reinterpret_cast<const float2*>(base + (size_t)(f0 + 32 + k) * NN + m0 + c2 * 2);
            }
        }
        #pragma unroll 8
        for (int k = 0; k < 32; ++k) {
            double2 aL = *reinterpret_cast<const double2*>(&As[k][tx * 2]);
            double2 aH = *reinterpret_cast<const double2*>(&As[k][tx * 2 + 32]);
            double2 bL = *reinterpret_cast<const double2*>(&Bs[k][ty * 2]);
            double2 bH = *reinterpret_cast<const double2*>(&Bs[k][ty * 2 + 32]);
            double a0 = aL.x, a1 = aL.y, a2 = aH.x, a3 = aH.y;
            double b0d = bL.x, b1d = bL.y, b2d = bH.x, b3d = bH.y;
            acc[0][0] = fma(a0, b0d, acc[0][0]);
            acc[0][1] = fma(a0, b1d, acc[0][1]);
            acc[0][2] = fma(a0, b2d, acc[0][2]);
            acc[0][3] = fma(a0, b3d, acc[0][3]);
            acc[1][0] = fma(a1, b0d, acc[1][0]);
            acc[1][1] = fma(a1, b1d, acc[1][1]);
            acc[1][2] = fma(a1, b2d, acc[1][2]);
            acc[1][3] = fma(a1, b3d, acc[1][3]);
            acc[2][0] = fma(a2, b0d, acc[2][0]);
            acc[2][1] = fma(a2, b1d, acc[2][1]);
            acc[2][2] = fma(a2, b2d, acc[2][2]);
            acc[2][3] = fma(a2, b3d, acc[2][3]);
            acc[3][0] = fma(a3, b0d, acc[3][0]);
            acc[3][1] = fma(a3, b1d, acc[3][1]);
            acc[3][2] = fma(a3, b2d, acc[3][2]);
            acc[3][3] = fma(a3, b3d, acc[3][3]);
        }
        __syncthreads();
    }
    const double* sqb = sq + (size_t)b * NN;
    bool mirror = (ti != tj);
    #pragma unroll
    for (int i = 0; i < 4; ++i) {
        int n = n0 + ((i & 2) ? 32 : 0) + tx * 2 + (i & 1);
        double sn = sqb[n];
        #pragma unroll
        for (int j = 0; j < 4; ++j) {
            int m = m0 + ((j & 2) ? 32 : 0) + ty * 2 + (j & 1);
            double d2 = sn + sqb[m] - 2.0 * acc[i][j];
            if (d2 < 0.0) d2 = 0.0;
            d2buf[((size_t)bb * NN + n) * NN + m] = d2;
            if (mirror) d2buf[((size_t)bb * NN + m) * NN + n] = d2;
        }
    }
}

// ---------------- K4: per-row 31st smallest (index KSEL of ascending sort, diag included)
__global__ __launch_bounds__(256) void k_select(const double* __restrict__ d2buf,
                                                double* __restrict__ sel, int b0) {
    int rowc = blockIdx.x * 4 + (threadIdx.x >> 6);  // row within chunk
    int lane = threadIdx.x & 63;
    const double* r = d2buf + (size_t)rowc * NN;
    double v[16];
    #pragma unroll
    for (int s = 0; s < 16; ++s) v[s] = r[s * 64 + lane];
    double kth = 0.0;
    for (int t = 0; t <= KSEL; ++t) {
        double mv = v[0]; int ms = 0;
        #pragma unroll
        for (int s = 1; s < 16; ++s) { if (v[s] < mv) { mv = v[s]; ms = s; } }
        int mid = ms * 64 + lane;
        #pragma unroll
        for (int off = 1; off < 64; off <<= 1) {
            double ov = __shfl_xor(mv, off);
            int oid  = __shfl_xor(mid, off);
            if (ov < mv || (ov == mv && oid < mid)) { mv = ov; mid = oid; }
        }
        kth = mv;
        if (t < KSEL) {
            #pragma unroll
            for (int s = 0; s < 16; ++s) {
                if (s * 64 + lane == mid) v[s] = 1e300;
            }
        }
    }
    if (lane == 0) sel[(size_t)b0 * NN + rowc] = sqrt(kth);
}

// ---------------- K5: R2[b] = (mean_n sel)^2
__global__ __launch_bounds__(256) void k_R(const double* __restrict__ sel,
                                           double* __restrict__ R2v, int b0) {
    int b = b0 + blockIdx.x;
    int tid = threadIdx.x;
    const double* s = sel + (size_t)b * NN;
    double acc = s[tid] + s[tid + 256] + s[tid + 512] + s[tid + 768];
    __shared__ double red[256];
    red[tid] = acc; __syncthreads();
    for (int st = 128; st > 0; st >>= 1) {
        if (tid < st) red[tid] += red[tid + st];
        __syncthreads();
    }
    if (tid == 0) { double R = red[0] / (double)NN; R2v[b] = R * R; }
}

// ---------------- K6: per-row counts fused over batches (adj row read once)
__global__ __launch_bounds__(256) void k_counts(const double* __restrict__ d2buf,
                                                const float* __restrict__ adj,
                                                const double* __restrict__ R2v,
                                                int* __restrict__ samplesN,
                                                int* __restrict__ neighborN,
                                                int* __restrict__ ssum, int b0, int c) {
    int n = blockIdx.x;          // row 0..1023
    int tid = threadIdx.x;
    int lane = tid & 63, wid = tid >> 6;
    const float* arow = adj + (size_t)n * NN;
    float a0 = arow[tid], a1 = arow[tid + 256], a2 = arow[tid + 512], a3 = arow[tid + 768];
    __shared__ int ws[2][4];
    for (int bb = 0; bb < c; ++bb) {
        int b = b0 + bb;
        double R2 = R2v[b];
        const double* r = d2buf + ((size_t)bb * NN + n) * NN;
        double d0 = r[tid], d1 = r[tid + 256], d2v = r[tid + 512], d3 = r[tid + 768];
        int cs = 0, cn = 0;
        if (d0 < R2) { cs++; if (a0 != 0.0f && d0 > 0.0) cn++; }
        if (d1 < R2) { cs++; if (a1 != 0.0f && d1 > 0.0) cn++; }
        if (d2v < R2) { cs++; if (a2 != 0.0f && d2v > 0.0) cn++; }
        if (d3 < R2) { cs++; if (a3 != 0.0f && d3 > 0.0) cn++; }
        #pragma unroll
        for (int off = 1; off < 64; off <<= 1) {
            cs += __shfl_xor(cs, off);
            cn += __shfl_xor(cn, off);
        }
        if (lane == 0) { ws[0][wid] = cs; ws[1][wid] = cn; }
        __syncthreads();
        if (tid == 0) {
            int ts = ws[0][0] + ws[0][1] + ws[0][2] + ws[0][3];
            int tn = ws[1][0] + ws[1][1] + ws[1][2] + ws[1][3];
            int g = b * NN + n;
            samplesN[g]  = ts;
            neighborN[g] = tn;
            atomicAdd(&ssum[b], ts);
        }
        __syncthreads();
    }
}

// ---------------- K8: fused score + stable double-argsort rank + keep mask
__global__ __launch_bounds__(1024) void k_rank(const int* __restrict__ samplesN,
                                               const int* __restrict__ neighborN,
                                               const int* __restrict__ ssum,
                                               const float* __restrict__ deg,
                                               const float* __restrict__ pptr,
                                               float* __restrict__ keepf,
                                               float* __restrict__ outScore) {
    int b = blockIdx.x;
    int i = threadIdx.x;
    int g = b * NN + i;
    float sv  = (float)samplesN[g];
    float nb  = (float)neighborN[g];
    float means = (float)ssum[b] / 1024.0f;
    float spatial  = nb / deg[i];
    float temporal = sv / (sv + means);
    float sc = (2.0f - spatial) - temporal;
    outScore[g] = sc;
    __shared__ float s[NN];
    s[i] = sc;
    __syncthreads();
    float si = s[i];
    int rank = 0;
    for (int j = 0; j < NN; ++j) {
        float sj = s[j];
        if (sj < si || (sj == si && j < i)) rank++;
    }
    float cut = (float)NN * pptr[0];
    keepf[g] = ((float)rank < cut) ? 1.0f : 0.0f;
}

// ---------------- K9: out = data * keep (broadcast over C,H)
__global__ __launch_bounds__(256) void k_apply(const float* __restrict__ data,
                                               const float* __restrict__ keepf,
                                               float* __restrict__ out) {
    size_t g4 = (size_t)blockIdx.x * 256 + threadIdx.x;
    size_t flat = g4 << 2;
    int w = (int)(flat & (NN - 1));
    int b = (int)(flat / ((size_t)NF * NN));
    float4 v = reinterpret_cast<const float4*>(data)[g4];
    const float4* kb = reinterpret_cast<const float4*>(keepf + b * NN + w);
    float4 kv = kb[0];
    float4 o;
    o.x = v.x * kv.x; o.y = v.y * kv.y; o.z = v.z * kv.z; o.w = v.w * kv.w;
    reinterpret_cast<float4*>(out)[g4] = o;
}

extern "C" void kernel_launch(void* const* d_in, const int* in_sizes, int n_in,
                              void* d_out, int out_size, void* d_ws, size_t ws_size,
                              hipStream_t stream) {
    const float* data = (const float*)d_in[0];
    const float* adj  = (const float*)d_in[1];
    const float* pptr = (const float*)d_in[4];
    float* out = (float*)d_out;
    float* outScore = out + (size_t)NB * NF * NN;

    char* w = (char*)d_ws;
    size_t off = 0;
    auto alloc = [&](size_t bytes) -> void* {
        off = (off + 255) & ~(size_t)255;
        void* p = w + off;
        off += bytes;
        return p;
    };
    double* meanv  = (double*)alloc((size_t)NB * NF * 8);
    double* invv   = (double*)alloc((size_t)NB * NF * 8);
    double* sq     = (double*)alloc((size_t)NB * NN * 8);
    double* psum   = (double*)alloc((size_t)NB * 8 * NN * 8);
    double* sel    = (double*)alloc((size_t)NB * NN * 8);
    double* R2v    = (double*)alloc((size_t)NB * 8);
    int* samplesN  = (int*)alloc((size_t)NB * NN * 4);
    int* neighborN = (int*)alloc((size_t)NB * NN * 4);
    int* ssum      = (int*)alloc((size_t)NB * 4);
    float* deg     = (float*)alloc((size_t)NN * 4);
    float* keepf   = (float*)alloc((size_t)NB * NN * 4);
    off = (off + 255) & ~(size_t)255;
    size_t rem = (ws_size > off) ? (ws_size - off) : 0;
    int chunk = (int)(rem / ((size_t)NN * NN * 8));
    if (chunk > NB) chunk = NB;
    if (chunk < 1) chunk = 1;
    double* d2buf = (double*)(w + off);

    hipMemsetAsync(ssum, 0, NB * 4, stream);
    k_stats<<<NB * NF / 4, 256, 0, stream>>>(data, meanv, invv);
    k_sq1<<<dim3(NB * 4, 8), 256, 0, stream>>>(data, meanv, invv, psum);
    k_sq2<<<NB * NN / 256, 256, 0, stream>>>(psum, sq);
    k_deg<<<NN / 4, 256, 0, stream>>>(adj, deg);

    for (int b0 = 0; b0 < NB; b0 += chunk) {
        int c = (NB - b0 < chunk) ? (NB - b0) : chunk;
        dim3 gg(136, 1, c);
        k_gemm_sym<<<gg, 256, 0, stream>>>(data, meanv, invv, sq, d2buf, b0);
        k_select<<<c * NN / 4, 256, 0, stream>>>(d2buf, sel, b0);
        k_R<<<c, 256, 0, stream>>>(sel, R2v, b0);
        k_counts<<<NN, 256, 0, stream>>>(d2buf, adj, R2v, samplesN, neighborN, ssum, b0, c);
    }

    k_rank<<<NB, 1024, 0, stream>>>(samplesN, neighborN, ssum, deg, pptr, keepf, outScore);
    k_apply<<<(NB * NF * NN) / (256 * 4), 256, 0, stream>>>(data, keepf, out);
}

// Round 14
// 609.965 us; speedup vs baseline: 1.2162x; 1.2162x over previous
//
#include <hip/hip_runtime.h>
#include <math.h>

#define NB 16
#define NF 768
#define NN 1024
#define KSEL 30

// ---------------- K1: per-(b,f) mean and 1/(std+1e-6); one wave per row
__global__ __launch_bounds__(256) void k_stats(const float* __restrict__ data,
                                               double* __restrict__ meanv,
                                               double* __restrict__ invv) {
    int bf = blockIdx.x * 4 + (threadIdx.x >> 6);
    int lane = threadIdx.x & 63;
    const float4* p = reinterpret_cast<const float4*>(data + (size_t)bf * NN);
    double s = 0.0, s2 = 0.0;
    #pragma unroll
    for (int r = 0; r < 4; ++r) {
        float4 v = p[r * 64 + lane];
        s  += (double)v.x + (double)v.y + (double)v.z + (double)v.w;
        s2 += (double)v.x * (double)v.x + (double)v.y * (double)v.y +
              (double)v.z * (double)v.z + (double)v.w * (double)v.w;
    }
    #pragma unroll
    for (int off = 1; off < 64; off <<= 1) {
        s  += __shfl_xor(s, off);
        s2 += __shfl_xor(s2, off);
    }
    if (lane == 0) {
        double mean = s / (double)NN;
        double var = (s2 - s * mean) / (double)(NN - 1);
        if (var < 0.0) var = 0.0;
        meanv[bf] = mean;
        invv[bf]  = 1.0 / (sqrt(var) + 1e-6);
    }
}

// ---------------- K2a: partial sq over f-chunks of 96 (512 blocks for parallelism)
__global__ __launch_bounds__(256) void k_sq1(const float* __restrict__ data,
                                             const double* __restrict__ meanv,
                                             const double* __restrict__ invv,
                                             double* __restrict__ psum) {
    int b = blockIdx.x >> 2;
    int n = ((blockIdx.x & 3) << 8) + threadIdx.x;
    int y = blockIdx.y;                 // f-chunk 0..7
    const float* base = data + (size_t)b * NF * NN;
    const double* mb = meanv + (size_t)b * NF;
    const double* ib = invv + (size_t)b * NF;
    double acc = 0.0;
    int f0 = y * 96;
    for (int f = f0; f < f0 + 96; ++f) {
        float x = base[(size_t)f * NN + n];
        float xn = (float)(((double)x - mb[f]) * ib[f]);
        acc = fma((double)xn, (double)xn, acc);
    }
    psum[((size_t)(b * 8 + y)) * NN + n] = acc;
}

// ---------------- K2b: reduce 8 partials -> sq[b,n]
__global__ __launch_bounds__(256) void k_sq2(const double* __restrict__ psum,
                                             double* __restrict__ sq) {
    int g = blockIdx.x * 256 + threadIdx.x;   // 0..16383
    int b = g >> 10, n = g & (NN - 1);
    double acc = 0.0;
    #pragma unroll
    for (int y = 0; y < 8; ++y) acc += psum[((size_t)(b * 8 + y)) * NN + n];
    sq[g] = acc;
}

// ---------------- K0: deg[n] = row-sum of adj; one wave per row
__global__ __launch_bounds__(256) void k_deg(const float* __restrict__ adj, float* __restrict__ deg) {
    int n = blockIdx.x * 4 + (threadIdx.x >> 6);
    int lane = threadIdx.x & 63;
    const float4* row = reinterpret_cast<const float4*>(adj + (size_t)n * NN);
    float s = 0.0f;
    #pragma unroll
    for (int r = 0; r < 4; ++r) {
        float4 v = row[r * 64 + lane];
        s += v.x + v.y + v.z + v.w;
    }
    #pragma unroll
    for (int off = 1; off < 64; off <<= 1) s += __shfl_xor(s, off);
    if (lane == 0) deg[n] = s;
}

// ---------------- K3: symmetric batched Gram + d2 epilogue (f64 accum)
// MIXED-PRECISION LDS, derived from the validated pipe model:
//  round-12 (A,B f64): 4 ds_read_b128/k -> LDS-bound (~430 cyc/CU-rotation).
//  round-9  (A,B f32): 2 reads + 8 cvt -> VALU-bound (~470).
//  Mixed: A f64 (2 reads, 0 cvt) + B f32 (1 read, 4 cvt) -> ~max(310,270).
// B values are f32-exact by construction, so (double)Bs[..] is bitwise
// identical to the f64 store. B float4 read = 4 distinct 16B addrs/wave
// (broadcast within ty-groups) = conflict-free. A unchanged from round 12.
__global__ __launch_bounds__(256) void k_gemm_sym(const float* __restrict__ data,
                                                  const double* __restrict__ meanv,
                                                  const double* __restrict__ invv,
                                                  const double* __restrict__ sq,
                                                  double* __restrict__ d2buf, int b0) {
    __shared__ double As[32][64];
    __shared__ float  Bs[32][64];
    int tid = threadIdx.x;
    int tx = tid & 15, ty = tid >> 4;
    // triangular decode over 16x16 tiles of 64: t in [0,136), ti <= tj
    int t = blockIdx.x;
    int ti = 0, rem = t;
    while (rem >= 16 - ti) { rem -= 16 - ti; ++ti; }
    int tj = ti + rem;
    int n0 = ti * 64, m0 = tj * 64;
    int bb = blockIdx.z;
    int b = b0 + bb;
    const float* base = data + (size_t)b * NF * NN;
    const double* mb = meanv + (size_t)b * NF;
    const double* ib = invv + (size_t)b * NF;
    double acc[4][4] = {{0.0}};
    for (int f0 = 0; f0 < NF; f0 += 32) {
        // stage 32 k-rows x 64 cols: 1024 float2 slots, 4 per thread
        #pragma unroll
        for (int r = 0; r < 4; ++r) {
            int idx = r * 256 + tid;   // 0..1023
            int k = idx >> 5;          // 0..31
            int c2 = idx & 31;         // float2 col 0..31
            double mk = mb[f0 + k], ik = ib[f0 + k];
            float2 a = *reinterpret_cast<const float2*>(base + (size_t)(f0 + k) * NN + n0 + c2 * 2);
            float2 c = *reinterpret_cast<const float2*>(base + (size_t)(f0 + k) * NN + m0 + c2 * 2);
            double2 da;
            da.x = (double)(float)(((double)a.x - mk) * ik);
            da.y = (double)(float)(((double)a.y - mk) * ik);
            float2 fc;
            fc.x = (float)(((double)c.x - mk) * ik);
            fc.y = (float)(((double)c.y - mk) * ik);
            *reinterpret_cast<double2*>(&As[k][c2 * 2]) = da;
            *reinterpret_cast<float2*>(&Bs[k][c2 * 2]) = fc;
        }
        __syncthreads();
        #pragma unroll 8
        for (int k = 0; k < 32; ++k) {
            double2 aL = *reinterpret_cast<const double2*>(&As[k][tx * 2]);
            double2 aH = *reinterpret_cast<const double2*>(&As[k][tx * 2 + 32]);
            float4  bq = *reinterpret_cast<const float4*>(&Bs[k][ty * 4]);
            double a0 = aL.x, a1 = aL.y, a2 = aH.x, a3 = aH.y;
            double b0d = (double)bq.x, b1d = (double)bq.y;
            double b2d = (double)bq.z, b3d = (double)bq.w;
            acc[0][0] = fma(a0, b0d, acc[0][0]);
            acc[0][1] = fma(a0, b1d, acc[0][1]);
            acc[0][2] = fma(a0, b2d, acc[0][2]);
            acc[0][3] = fma(a0, b3d, acc[0][3]);
            acc[1][0] = fma(a1, b0d, acc[1][0]);
            acc[1][1] = fma(a1, b1d, acc[1][1]);
            acc[1][2] = fma(a1, b2d, acc[1][2]);
            acc[1][3] = fma(a1, b3d, acc[1][3]);
            acc[2][0] = fma(a2, b0d, acc[2][0]);
            acc[2][1] = fma(a2, b1d, acc[2][1]);
            acc[2][2] = fma(a2, b2d, acc[2][2]);
            acc[2][3] = fma(a2, b3d, acc[2][3]);
            acc[3][0] = fma(a3, b0d, acc[3][0]);
            acc[3][1] = fma(a3, b1d, acc[3][1]);
            acc[3][2] = fma(a3, b2d, acc[3][2]);
            acc[3][3] = fma(a3, b3d, acc[3][3]);
        }
        __syncthreads();
    }
    const double* sqb = sq + (size_t)b * NN;
    bool mirror = (ti != tj);
    #pragma unroll
    for (int i = 0; i < 4; ++i) {
        int n = n0 + ((i & 2) ? 32 : 0) + tx * 2 + (i & 1);
        double sn = sqb[n];
        #pragma unroll
        for (int j = 0; j < 4; ++j) {
            int m = m0 + ty * 4 + j;
            double d2 = sn + sqb[m] - 2.0 * acc[i][j];
            if (d2 < 0.0) d2 = 0.0;
            d2buf[((size_t)bb * NN + n) * NN + m] = d2;
            if (mirror) d2buf[((size_t)bb * NN + m) * NN + n] = d2;
        }
    }
}

// ---------------- K4: per-row 31st smallest (index KSEL of ascending sort, diag included)
__global__ __launch_bounds__(256) void k_select(const double* __restrict__ d2buf,
                                                double* __restrict__ sel, int b0) {
    int rowc = blockIdx.x * 4 + (threadIdx.x >> 6);  // row within chunk
    int lane = threadIdx.x & 63;
    const double* r = d2buf + (size_t)rowc * NN;
    double v[16];
    #pragma unroll
    for (int s = 0; s < 16; ++s) v[s] = r[s * 64 + lane];
    double kth = 0.0;
    for (int t = 0; t <= KSEL; ++t) {
        double mv = v[0]; int ms = 0;
        #pragma unroll
        for (int s = 1; s < 16; ++s) { if (v[s] < mv) { mv = v[s]; ms = s; } }
        int mid = ms * 64 + lane;
        #pragma unroll
        for (int off = 1; off < 64; off <<= 1) {
            double ov = __shfl_xor(mv, off);
            int oid  = __shfl_xor(mid, off);
            if (ov < mv || (ov == mv && oid < mid)) { mv = ov; mid = oid; }
        }
        kth = mv;
        if (t < KSEL) {
            #pragma unroll
            for (int s = 0; s < 16; ++s) {
                if (s * 64 + lane == mid) v[s] = 1e300;
            }
        }
    }
    if (lane == 0) sel[(size_t)b0 * NN + rowc] = sqrt(kth);
}

// ---------------- K5: R2[b] = (mean_n sel)^2
__global__ __launch_bounds__(256) void k_R(const double* __restrict__ sel,
                                           double* __restrict__ R2v, int b0) {
    int b = b0 + blockIdx.x;
    int tid = threadIdx.x;
    const double* s = sel + (size_t)b * NN;
    double acc = s[tid] + s[tid + 256] + s[tid + 512] + s[tid + 768];
    __shared__ double red[256];
    red[tid] = acc; __syncthreads();
    for (int st = 128; st > 0; st >>= 1) {
        if (tid < st) red[tid] += red[tid + st];
        __syncthreads();
    }
    if (tid == 0) { double R = red[0] / (double)NN; R2v[b] = R * R; }
}

// ---------------- K6: per-row counts fused over batches (adj row read once)
__global__ __launch_bounds__(256) void k_counts(const double* __restrict__ d2buf,
                                                const float* __restrict__ adj,
                                                const double* __restrict__ R2v,
                                                int* __restrict__ samplesN,
                                                int* __restrict__ neighborN,
                                                int b0, int c) {
    int n = blockIdx.x;          // row 0..1023
    int tid = threadIdx.x;
    int lane = tid & 63, wid = tid >> 6;
    const float* arow = adj + (size_t)n * NN;
    float a0 = arow[tid], a1 = arow[tid + 256], a2 = arow[tid + 512], a3 = arow[tid + 768];
    __shared__ int ws[2][4];
    for (int bb = 0; bb < c; ++bb) {
        int b = b0 + bb;
        double R2 = R2v[b];
        const double* r = d2buf + ((size_t)bb * NN + n) * NN;
        double d0 = r[tid], d1 = r[tid + 256], d2v = r[tid + 512], d3 = r[tid + 768];
        int cs = 0, cn = 0;
        if (d0 < R2) { cs++; if (a0 != 0.0f && d0 > 0.0) cn++; }
        if (d1 < R2) { cs++; if (a1 != 0.0f && d1 > 0.0) cn++; }
        if (d2v < R2) { cs++; if (a2 != 0.0f && d2v > 0.0) cn++; }
        if (d3 < R2) { cs++; if (a3 != 0.0f && d3 > 0.0) cn++; }
        #pragma unroll
        for (int off = 1; off < 64; off <<= 1) {
            cs += __shfl_xor(cs, off);
            cn += __shfl_xor(cn, off);
        }
        if (lane == 0) { ws[0][wid] = cs; ws[1][wid] = cn; }
        __syncthreads();
        if (tid == 0) {
            int g = b * NN + n;
            samplesN[g]  = ws[0][0] + ws[0][1] + ws[0][2] + ws[0][3];
            neighborN[g] = ws[1][0] + ws[1][1] + ws[1][2] + ws[1][3];
        }
        __syncthreads();
    }
}

// ---------------- K8: fused score + batch-sum + stable double-argsort rank + keep
// int sums of samplesN (<2^20) are f32-exact, so means == reference's f32 mean.
__global__ __launch_bounds__(1024) void k_rank(const int* __restrict__ samplesN,
                                               const int* __restrict__ neighborN,
                                               const float* __restrict__ deg,
                                               const float* __restrict__ pptr,
                                               float* __restrict__ keepf,
                                               float* __restrict__ outScore) {
    int b = blockIdx.x;
    int i = threadIdx.x;
    int g = b * NN + i;
    int sN = samplesN[g];
    __shared__ int rsum[NN];
    rsum[i] = sN; __syncthreads();
    for (int st = 512; st > 0; st >>= 1) {
        if (i < st) rsum[i] += rsum[i + st];
        __syncthreads();
    }
    float means = (float)rsum[0] / 1024.0f;
    float sv  = (float)sN;
    float nb  = (float)neighborN[g];
    float spatial  = nb / deg[i];
    float temporal = sv / (sv + means);
    float sc = (2.0f - spatial) - temporal;
    outScore[g] = sc;
    __shared__ float s[NN];
    s[i] = sc;
    __syncthreads();
    float si = s[i];
    int rank = 0;
    for (int j = 0; j < NN; ++j) {
        float sj = s[j];
        if (sj < si || (sj == si && j < i)) rank++;
    }
    float cut = (float)NN * pptr[0];
    keepf[g] = ((float)rank < cut) ? 1.0f : 0.0f;
}

// ---------------- K9: out = data * keep (broadcast over C,H)
__global__ __launch_bounds__(256) void k_apply(const float* __restrict__ data,
                                               const float* __restrict__ keepf,
                                               float* __restrict__ out) {
    size_t g4 = (size_t)blockIdx.x * 256 + threadIdx.x;
    size_t flat = g4 << 2;
    int w = (int)(flat & (NN - 1));
    int b = (int)(flat / ((size_t)NF * NN));
    float4 v = reinterpret_cast<const float4*>(data)[g4];
    const float4* kb = reinterpret_cast<const float4*>(keepf + b * NN + w);
    float4 kv = kb[0];
    float4 o;
    o.x = v.x * kv.x; o.y = v.y * kv.y; o.z = v.z * kv.z; o.w = v.w * kv.w;
    reinterpret_cast<float4*>(out)[g4] = o;
}

extern "C" void kernel_launch(void* const* d_in, const int* in_sizes, int n_in,
                              void* d_out, int out_size, void* d_ws, size_t ws_size,
                              hipStream_t stream) {
    const float* data = (const float*)d_in[0];
    const float* adj  = (const float*)d_in[1];
    const float* pptr = (const float*)d_in[4];
    float* out = (float*)d_out;
    float* outScore = out + (size_t)NB * NF * NN;

    char* w = (char*)d_ws;
    size_t off = 0;
    auto alloc = [&](size_t bytes) -> void* {
        off = (off + 255) & ~(size_t)255;
        void* p = w + off;
        off += bytes;
        return p;
    };
    double* meanv  = (double*)alloc((size_t)NB * NF * 8);
    double* invv   = (double*)alloc((size_t)NB * NF * 8);
    double* sq     = (double*)alloc((size_t)NB * NN * 8);
    double* psum   = (double*)alloc((size_t)NB * 8 * NN * 8);
    double* sel    = (double*)alloc((size_t)NB * NN * 8);
    double* R2v    = (double*)alloc((size_t)NB * 8);
    int* samplesN  = (int*)alloc((size_t)NB * NN * 4);
    int* neighborN = (int*)alloc((size_t)NB * NN * 4);
    float* deg     = (float*)alloc((size_t)NN * 4);
    float* keepf   = (float*)alloc((size_t)NB * NN * 4);
    off = (off + 255) & ~(size_t)255;
    size_t rem = (ws_size > off) ? (ws_size - off) : 0;
    int chunk = (int)(rem / ((size_t)NN * NN * 8));
    if (chunk > NB) chunk = NB;
    if (chunk < 1) chunk = 1;
    double* d2buf = (double*)(w + off);

    k_stats<<<NB * NF / 4, 256, 0, stream>>>(data, meanv, invv);
    k_sq1<<<dim3(NB * 4, 8), 256, 0, stream>>>(data, meanv, invv, psum);
    k_sq2<<<NB * NN / 256, 256, 0, stream>>>(psum, sq);
    k_deg<<<NN / 4, 256, 0, stream>>>(adj, deg);

    for (int b0 = 0; b0 < NB; b0 += chunk) {
        int c = (NB - b0 < chunk) ? (NB - b0) : chunk;
        dim3 gg(136, 1, c);
        k_gemm_sym<<<gg, 256, 0, stream>>>(data, meanv, invv, sq, d2buf, b0);
        k_select<<<c * NN / 4, 256, 0, stream>>>(d2buf, sel, b0);
        k_R<<<c, 256, 0, stream>>>(sel, R2v, b0);
        k_counts<<<NN, 256, 0, stream>>>(d2buf, adj, R2v, samplesN, neighborN, b0, c);
    }

    k_rank<<<NB, 1024, 0, stream>>>(samplesN, neighborN, deg, pptr, keepf, outScore);
    k_apply<<<(NB * NF * NN) / (256 * 4), 256, 0, stream>>>(data, keepf, out);
}

// Round 15
// 566.208 us; speedup vs baseline: 1.3102x; 1.0773x over previous
//
#include <hip/hip_runtime.h>
#include <math.h>

#define NB 16
#define NF 768
#define NN 1024
#define KSEL 30

// ---------------- K1: per-(b,f) mean and 1/(std+1e-6); one wave per row
__global__ __launch_bounds__(256) void k_stats(const float* __restrict__ data,
                                               double* __restrict__ meanv,
                                               double* __restrict__ invv) {
    int bf = blockIdx.x * 4 + (threadIdx.x >> 6);
    int lane = threadIdx.x & 63;
    const float4* p = reinterpret_cast<const float4*>(data + (size_t)bf * NN);
    double s = 0.0, s2 = 0.0;
    #pragma unroll
    for (int r = 0; r < 4; ++r) {
        float4 v = p[r * 64 + lane];
        s  += (double)v.x + (double)v.y + (double)v.z + (double)v.w;
        s2 += (double)v.x * (double)v.x + (double)v.y * (double)v.y +
              (double)v.z * (double)v.z + (double)v.w * (double)v.w;
    }
    #pragma unroll
    for (int off = 1; off < 64; off <<= 1) {
        s  += __shfl_xor(s, off);
        s2 += __shfl_xor(s2, off);
    }
    if (lane == 0) {
        double mean = s / (double)NN;
        double var = (s2 - s * mean) / (double)(NN - 1);
        if (var < 0.0) var = 0.0;
        meanv[bf] = mean;
        invv[bf]  = 1.0 / (sqrt(var) + 1e-6);
    }
}

// ---------------- K2a: partial sq over f-chunks of 96 (512 blocks for parallelism)
__global__ __launch_bounds__(256) void k_sq1(const float* __restrict__ data,
                                             const double* __restrict__ meanv,
                                             const double* __restrict__ invv,
                                             double* __restrict__ psum) {
    int b = blockIdx.x >> 2;
    int n = ((blockIdx.x & 3) << 8) + threadIdx.x;
    int y = blockIdx.y;                 // f-chunk 0..7
    const float* base = data + (size_t)b * NF * NN;
    const double* mb = meanv + (size_t)b * NF;
    const double* ib = invv + (size_t)b * NF;
    double acc = 0.0;
    int f0 = y * 96;
    for (int f = f0; f < f0 + 96; ++f) {
        float x = base[(size_t)f * NN + n];
        float xn = (float)(((double)x - mb[f]) * ib[f]);
        acc = fma((double)xn, (double)xn, acc);
    }
    psum[((size_t)(b * 8 + y)) * NN + n] = acc;
}

// ---------------- K2b: reduce 8 partials -> sq[b,n]
__global__ __launch_bounds__(256) void k_sq2(const double* __restrict__ psum,
                                             double* __restrict__ sq) {
    int g = blockIdx.x * 256 + threadIdx.x;   // 0..16383
    int b = g >> 10, n = g & (NN - 1);
    double acc = 0.0;
    #pragma unroll
    for (int y = 0; y < 8; ++y) acc += psum[((size_t)(b * 8 + y)) * NN + n];
    sq[g] = acc;
}

// ---------------- K0: deg[n] = row-sum of adj; one wave per row
__global__ __launch_bounds__(256) void k_deg(const float* __restrict__ adj, float* __restrict__ deg) {
    int n = blockIdx.x * 4 + (threadIdx.x >> 6);
    int lane = threadIdx.x & 63;
    const float4* row = reinterpret_cast<const float4*>(adj + (size_t)n * NN);
    float s = 0.0f;
    #pragma unroll
    for (int r = 0; r < 4; ++r) {
        float4 v = row[r * 64 + lane];
        s += v.x + v.y + v.z + v.w;
    }
    #pragma unroll
    for (int off = 1; off < 64; off <<= 1) s += __shfl_xor(s, off);
    if (lane == 0) deg[n] = s;
}

// ---------------- K3: symmetric batched Gram + d2 epilogue (f64 accum)
// Round-13 proven config (best measured gemm: 385 us, conflicts 0, no spill):
// all-f64 LDS, conflict-free 16B-stride double2 fragment reads/writes,
// 64x64 tiles, 4x4 acc, 136 triangular pairs + mirror. Round-14's mixed
// f64/f32 LDS regressed (431 us) - reverted.
__global__ __launch_bounds__(256) void k_gemm_sym(const float* __restrict__ data,
                                                  const double* __restrict__ meanv,
                                                  const double* __restrict__ invv,
                                                  const double* __restrict__ sq,
                                                  double* __restrict__ d2buf, int b0) {
    __shared__ double As[32][64];
    __shared__ double Bs[32][64];
    int tid = threadIdx.x;
    int tx = tid & 15, ty = tid >> 4;
    // triangular decode over 16x16 tiles of 64: t in [0,136), ti <= tj
    int t = blockIdx.x;
    int ti = 0, rem = t;
    while (rem >= 16 - ti) { rem -= 16 - ti; ++ti; }
    int tj = ti + rem;
    int n0 = ti * 64, m0 = tj * 64;
    int bb = blockIdx.z;
    int b = b0 + bb;
    const float* base = data + (size_t)b * NF * NN;
    const double* mb = meanv + (size_t)b * NF;
    const double* ib = invv + (size_t)b * NF;
    double acc[4][4] = {{0.0}};
    for (int f0 = 0; f0 < NF; f0 += 32) {
        // stage 32 k-rows x 64 cols: 1024 float2 slots, 4 per thread
        #pragma unroll
        for (int r = 0; r < 4; ++r) {
            int idx = r * 256 + tid;   // 0..1023
            int k = idx >> 5;          // 0..31
            int c2 = idx & 31;         // float2 col 0..31
            double mk = mb[f0 + k], ik = ib[f0 + k];
            float2 a = *reinterpret_cast<const float2*>(base + (size_t)(f0 + k) * NN + n0 + c2 * 2);
            float2 c = *reinterpret_cast<const float2*>(base + (size_t)(f0 + k) * NN + m0 + c2 * 2);
            double2 da, dc;
            da.x = (double)(float)(((double)a.x - mk) * ik);
            da.y = (double)(float)(((double)a.y - mk) * ik);
            dc.x = (double)(float)(((double)c.x - mk) * ik);
            dc.y = (double)(float)(((double)c.y - mk) * ik);
            *reinterpret_cast<double2*>(&As[k][c2 * 2]) = da;
            *reinterpret_cast<double2*>(&Bs[k][c2 * 2]) = dc;
        }
        __syncthreads();
        #pragma unroll 8
        for (int k = 0; k < 32; ++k) {
            double2 aL = *reinterpret_cast<const double2*>(&As[k][tx * 2]);
            double2 aH = *reinterpret_cast<const double2*>(&As[k][tx * 2 + 32]);
            double2 bL = *reinterpret_cast<const double2*>(&Bs[k][ty * 2]);
            double2 bH = *reinterpret_cast<const double2*>(&Bs[k][ty * 2 + 32]);
            double a0 = aL.x, a1 = aL.y, a2 = aH.x, a3 = aH.y;
            double b0d = bL.x, b1d = bL.y, b2d = bH.x, b3d = bH.y;
            acc[0][0] = fma(a0, b0d, acc[0][0]);
            acc[0][1] = fma(a0, b1d, acc[0][1]);
            acc[0][2] = fma(a0, b2d, acc[0][2]);
            acc[0][3] = fma(a0, b3d, acc[0][3]);
            acc[1][0] = fma(a1, b0d, acc[1][0]);
            acc[1][1] = fma(a1, b1d, acc[1][1]);
            acc[1][2] = fma(a1, b2d, acc[1][2]);
            acc[1][3] = fma(a1, b3d, acc[1][3]);
            acc[2][0] = fma(a2, b0d, acc[2][0]);
            acc[2][1] = fma(a2, b1d, acc[2][1]);
            acc[2][2] = fma(a2, b2d, acc[2][2]);
            acc[2][3] = fma(a2, b3d, acc[2][3]);
            acc[3][0] = fma(a3, b0d, acc[3][0]);
            acc[3][1] = fma(a3, b1d, acc[3][1]);
            acc[3][2] = fma(a3, b2d, acc[3][2]);
            acc[3][3] = fma(a3, b3d, acc[3][3]);
        }
        __syncthreads();
    }
    const double* sqb = sq + (size_t)b * NN;
    bool mirror = (ti != tj);
    #pragma unroll
    for (int i = 0; i < 4; ++i) {
        int n = n0 + ((i & 2) ? 32 : 0) + tx * 2 + (i & 1);
        double sn = sqb[n];
        #pragma unroll
        for (int j = 0; j < 4; ++j) {
            int m = m0 + ((j & 2) ? 32 : 0) + ty * 2 + (j & 1);
            double d2 = sn + sqb[m] - 2.0 * acc[i][j];
            if (d2 < 0.0) d2 = 0.0;
            d2buf[((size_t)bb * NN + n) * NN + m] = d2;
            if (mirror) d2buf[((size_t)bb * NN + m) * NN + n] = d2;
        }
    }
}

// ---------------- K4: per-row 31st smallest (index KSEL of ascending sort, diag included)
__global__ __launch_bounds__(256) void k_select(const double* __restrict__ d2buf,
                                                double* __restrict__ sel, int b0) {
    int rowc = blockIdx.x * 4 + (threadIdx.x >> 6);  // row within chunk
    int lane = threadIdx.x & 63;
    const double* r = d2buf + (size_t)rowc * NN;
    double v[16];
    #pragma unroll
    for (int s = 0; s < 16; ++s) v[s] = r[s * 64 + lane];
    double kth = 0.0;
    for (int t = 0; t <= KSEL; ++t) {
        double mv = v[0]; int ms = 0;
        #pragma unroll
        for (int s = 1; s < 16; ++s) { if (v[s] < mv) { mv = v[s]; ms = s; } }
        int mid = ms * 64 + lane;
        #pragma unroll
        for (int off = 1; off < 64; off <<= 1) {
            double ov = __shfl_xor(mv, off);
            int oid  = __shfl_xor(mid, off);
            if (ov < mv || (ov == mv && oid < mid)) { mv = ov; mid = oid; }
        }
        kth = mv;
        if (t < KSEL) {
            #pragma unroll
            for (int s = 0; s < 16; ++s) {
                if (s * 64 + lane == mid) v[s] = 1e300;
            }
        }
    }
    if (lane == 0) sel[(size_t)b0 * NN + rowc] = sqrt(kth);
}

// ---------------- K5: R2[b] = (mean_n sel)^2
__global__ __launch_bounds__(256) void k_R(const double* __restrict__ sel,
                                           double* __restrict__ R2v, int b0) {
    int b = b0 + blockIdx.x;
    int tid = threadIdx.x;
    const double* s = sel + (size_t)b * NN;
    double acc = s[tid] + s[tid + 256] + s[tid + 512] + s[tid + 768];
    __shared__ double red[256];
    red[tid] = acc; __syncthreads();
    for (int st = 128; st > 0; st >>= 1) {
        if (tid < st) red[tid] += red[tid + st];
        __syncthreads();
    }
    if (tid == 0) { double R = red[0] / (double)NN; R2v[b] = R * R; }
}

// ---------------- K6: per-row counts fused over batches (adj row read once)
__global__ __launch_bounds__(256) void k_counts(const double* __restrict__ d2buf,
                                                const float* __restrict__ adj,
                                                const double* __restrict__ R2v,
                                                int* __restrict__ samplesN,
                                                int* __restrict__ neighborN,
                                                int b0, int c) {
    int n = blockIdx.x;          // row 0..1023
    int tid = threadIdx.x;
    int lane = tid & 63, wid = tid >> 6;
    const float* arow = adj + (size_t)n * NN;
    float a0 = arow[tid], a1 = arow[tid + 256], a2 = arow[tid + 512], a3 = arow[tid + 768];
    __shared__ int ws[2][4];
    for (int bb = 0; bb < c; ++bb) {
        int b = b0 + bb;
        double R2 = R2v[b];
        const double* r = d2buf + ((size_t)bb * NN + n) * NN;
        double d0 = r[tid], d1 = r[tid + 256], d2v = r[tid + 512], d3 = r[tid + 768];
        int cs = 0, cn = 0;
        if (d0 < R2) { cs++; if (a0 != 0.0f && d0 > 0.0) cn++; }
        if (d1 < R2) { cs++; if (a1 != 0.0f && d1 > 0.0) cn++; }
        if (d2v < R2) { cs++; if (a2 != 0.0f && d2v > 0.0) cn++; }
        if (d3 < R2) { cs++; if (a3 != 0.0f && d3 > 0.0) cn++; }
        #pragma unroll
        for (int off = 1; off < 64; off <<= 1) {
            cs += __shfl_xor(cs, off);
            cn += __shfl_xor(cn, off);
        }
        if (lane == 0) { ws[0][wid] = cs; ws[1][wid] = cn; }
        __syncthreads();
        if (tid == 0) {
            int g = b * NN + n;
            samplesN[g]  = ws[0][0] + ws[0][1] + ws[0][2] + ws[0][3];
            neighborN[g] = ws[1][0] + ws[1][1] + ws[1][2] + ws[1][3];
        }
        __syncthreads();
    }
}

// ---------------- K8: fused score + batch-sum + stable double-argsort rank + keep
// int sums of samplesN (<2^20) are f32-exact, so means == reference's f32 mean.
__global__ __launch_bounds__(1024) void k_rank(const int* __restrict__ samplesN,
                                               const int* __restrict__ neighborN,
                                               const float* __restrict__ deg,
                                               const float* __restrict__ pptr,
                                               float* __restrict__ keepf,
                                               float* __restrict__ outScore) {
    int b = blockIdx.x;
    int i = threadIdx.x;
    int g = b * NN + i;
    int sN = samplesN[g];
    __shared__ int rsum[NN];
    rsum[i] = sN; __syncthreads();
    for (int st = 512; st > 0; st >>= 1) {
        if (i < st) rsum[i] += rsum[i + st];
        __syncthreads();
    }
    float means = (float)rsum[0] / 1024.0f;
    float sv  = (float)sN;
    float nb  = (float)neighborN[g];
    float spatial  = nb / deg[i];
    float temporal = sv / (sv + means);
    float sc = (2.0f - spatial) - temporal;
    outScore[g] = sc;
    __shared__ float s[NN];
    s[i] = sc;
    __syncthreads();
    float si = s[i];
    int rank = 0;
    for (int j = 0; j < NN; ++j) {
        float sj = s[j];
        if (sj < si || (sj == si && j < i)) rank++;
    }
    float cut = (float)NN * pptr[0];
    keepf[g] = ((float)rank < cut) ? 1.0f : 0.0f;
}

// ---------------- K9: out = data * keep (broadcast over C,H)
__global__ __launch_bounds__(256) void k_apply(const float* __restrict__ data,
                                               const float* __restrict__ keepf,
                                               float* __restrict__ out) {
    size_t g4 = (size_t)blockIdx.x * 256 + threadIdx.x;
    size_t flat = g4 << 2;
    int w = (int)(flat & (NN - 1));
    int b = (int)(flat / ((size_t)NF * NN));
    float4 v = reinterpret_cast<const float4*>(data)[g4];
    const float4* kb = reinterpret_cast<const float4*>(keepf + b * NN + w);
    float4 kv = kb[0];
    float4 o;
    o.x = v.x * kv.x; o.y = v.y * kv.y; o.z = v.z * kv.z; o.w = v.w * kv.w;
    reinterpret_cast<float4*>(out)[g4] = o;
}

extern "C" void kernel_launch(void* const* d_in, const int* in_sizes, int n_in,
                              void* d_out, int out_size, void* d_ws, size_t ws_size,
                              hipStream_t stream) {
    const float* data = (const float*)d_in[0];
    const float* adj  = (const float*)d_in[1];
    const float* pptr = (const float*)d_in[4];
    float* out = (float*)d_out;
    float* outScore = out + (size_t)NB * NF * NN;

    char* w = (char*)d_ws;
    size_t off = 0;
    auto alloc = [&](size_t bytes) -> void* {
        off = (off + 255) & ~(size_t)255;
        void* p = w + off;
        off += bytes;
        return p;
    };
    double* meanv  = (double*)alloc((size_t)NB * NF * 8);
    double* invv   = (double*)alloc((size_t)NB * NF * 8);
    double* sq     = (double*)alloc((size_t)NB * NN * 8);
    double* psum   = (double*)alloc((size_t)NB * 8 * NN * 8);
    double* sel    = (double*)alloc((size_t)NB * NN * 8);
    double* R2v    = (double*)alloc((size_t)NB * 8);
    int* samplesN  = (int*)alloc((size_t)NB * NN * 4);
    int* neighborN = (int*)alloc((size_t)NB * NN * 4);
    float* deg     = (float*)alloc((size_t)NN * 4);
    float* keepf   = (float*)alloc((size_t)NB * NN * 4);
    off = (off + 255) & ~(size_t)255;
    size_t rem = (ws_size > off) ? (ws_size - off) : 0;
    int chunk = (int)(rem / ((size_t)NN * NN * 8));
    if (chunk > NB) chunk = NB;
    if (chunk < 1) chunk = 1;
    double* d2buf = (double*)(w + off);

    k_stats<<<NB * NF / 4, 256, 0, stream>>>(data, meanv, invv);
    k_sq1<<<dim3(NB * 4, 8), 256, 0, stream>>>(data, meanv, invv, psum);
    k_sq2<<<NB * NN / 256, 256, 0, stream>>>(psum, sq);
    k_deg<<<NN / 4, 256, 0, stream>>>(adj, deg);

    for (int b0 = 0; b0 < NB; b0 += chunk) {
        int c = (NB - b0 < chunk) ? (NB - b0) : chunk;
        dim3 gg(136, 1, c);
        k_gemm_sym<<<gg, 256, 0, stream>>>(data, meanv, invv, sq, d2buf, b0);
        k_select<<<c * NN / 4, 256, 0, stream>>>(d2buf, sel, b0);
        k_R<<<c, 256, 0, stream>>>(sel, R2v, b0);
        k_counts<<<NN, 256, 0, stream>>>(d2buf, adj, R2v, samplesN, neighborN, b0, c);
    }

    k_rank<<<NB, 1024, 0, stream>>>(samplesN, neighborN, deg, pptr, keepf, outScore);
    k_apply<<<(NB * NF * NN) / (256 * 4), 256, 0, stream>>>(data, keepf, out);
}